// Round 12
// baseline (230.386 us; speedup 1.0000x reference)
//
#include <hip/hip_runtime.h>
#include <hip/hip_bf16.h>

// GraphConv x2 via dst-sorted CSR gather (no float atomics):
//   gather1:    aggm = mean_e w*x[src]
//   node_fused: lane=node, wave-uniform scalar weight loads, LDS act tile
//               read column-wise at stride 65 (2-way bank = free)
//   gather2:    out = mean_e w*hr[src] + hro
// CSR build: hist assigns rank[e]=atomicAdd(deg[d],1) with 4-edge ILP per
// thread (R11 post-mortem: 1-edge/thread made hist a latency chain, 46us);
// fill_csr is atomic-free (slot = base[d]+rank[e]), also 4-edge ILP.

#define NF 64

// ---------------- dtype detection (int64 vs int32 edge_index) ---------------
__global__ void detect_i64(const unsigned* __restrict__ raw, int* __restrict__ flag, int E) {
    __shared__ unsigned red[256];
    unsigned v = 0;
    int lim = (E < 4096) ? E : 4096;
    for (int i = threadIdx.x; i < lim; i += 256) v |= raw[2 * i + 1];
    red[threadIdx.x] = v;
    __syncthreads();
    for (int s = 128; s > 0; s >>= 1) {
        if (threadIdx.x < s) red[threadIdx.x] |= red[threadIdx.x + s];
        __syncthreads();
    }
    if (threadIdx.x == 0) *flag = (red[0] == 0) ? 1 : 0;  // high dwords zero => int64
}

// ------- histogram of dst + packed (dst,rank) records; 4-edge ILP -----------
__global__ __launch_bounds__(256) void hist(const void* __restrict__ raw,
                                            const int* __restrict__ flag,
                                            int* __restrict__ deg,
                                            int2* __restrict__ dr, int E) {
    int e0 = blockIdx.x * 1024 + threadIdx.x;
    int fl = *flag;
    int d[4];
#pragma unroll
    for (int j = 0; j < 4; ++j) {
        int e = e0 + j * 256;
        d[j] = 0;
        if (e < E) {
            if (fl) d[j] = (int)__builtin_nontemporal_load(((const long long*)raw) + E + e);
            else    d[j] = __builtin_nontemporal_load(((const int*)raw) + E + e);
        }
    }
    int r[4];
#pragma unroll
    for (int j = 0; j < 4; ++j) {
        int e = e0 + j * 256;
        if (e < E) r[j] = atomicAdd(&deg[d[j]], 1);
    }
#pragma unroll
    for (int j = 0; j < 4; ++j) {
        int e = e0 + j * 256;
        if (e < E) dr[e] = make_int2(d[j], r[j]);
    }
}

// ---------------- exclusive scan (3 kernels) ---------------------------------
__global__ __launch_bounds__(1024) void scan_k1(const int* __restrict__ deg,
                                                int* __restrict__ base,
                                                int* __restrict__ bsums, int N) {
    __shared__ int tmp[1024];
    int tid = threadIdx.x;
    int i = blockIdx.x * 1024 + tid;
    int v = (i < N) ? deg[i] : 0;
    tmp[tid] = v;
    __syncthreads();
    for (int off = 1; off < 1024; off <<= 1) {
        int t = (tid >= off) ? tmp[tid - off] : 0;
        __syncthreads();
        tmp[tid] += t;
        __syncthreads();
    }
    if (i < N) base[i] = tmp[tid] - v;
    if (tid == 1023) bsums[blockIdx.x] = tmp[tid];
}

__global__ __launch_bounds__(256) void scan_k2(int* __restrict__ bsums, int nb) {
    __shared__ int tmp[256];
    int tid = threadIdx.x;
    int v = (tid < nb) ? bsums[tid] : 0;
    tmp[tid] = v;
    __syncthreads();
    for (int off = 1; off < 256; off <<= 1) {
        int t = (tid >= off) ? tmp[tid - off] : 0;
        __syncthreads();
        tmp[tid] += t;
        __syncthreads();
    }
    if (tid < nb) bsums[tid] = tmp[tid] - v;
}

__global__ __launch_bounds__(1024) void scan_k3(int* __restrict__ base,
                                                const int* __restrict__ bsums, int N) {
    int i = blockIdx.x * 1024 + threadIdx.x;
    if (i >= N) return;
    base[i] += bsums[blockIdx.x];
}

// ---------------- weight prep: transpose into [k][f] layouts -----------------
__global__ __launch_bounds__(256) void wprep(
    const float* __restrict__ Wrel1, const float* __restrict__ Wroot1,
    const float* __restrict__ Wrel2, const float* __restrict__ Wroot2,
    float* __restrict__ W1relT, float* __restrict__ W1rootT,
    float* __restrict__ W2T) {
    int t = threadIdx.x;
    for (int i = t; i < 4096; i += 256) {
        int f = i >> 6, k = i & 63;
        W1relT[k * 64 + f]  = Wrel1[f * 64 + k];
        W1rootT[k * 64 + f] = Wroot1[f * 64 + k];
        W2T[k * 64 + f] = (f < 32) ? Wrel2[f * 64 + k] : Wroot2[(f - 32) * 64 + k];
    }
}

// ---------------- fill CSR slots: atomic-free, 4-edge ILP --------------------
__global__ __launch_bounds__(256) void fill_csr(const void* __restrict__ raw,
                                                const int* __restrict__ flag,
                                                const float* __restrict__ ea,
                                                const int2* __restrict__ dr,
                                                const int* __restrict__ base,
                                                long long* __restrict__ csr, int E) {
    int e0 = blockIdx.x * 1024 + threadIdx.x;
    int fl = *flag;
    int s[4]; float w[4]; int2 drv[4];
#pragma unroll
    for (int j = 0; j < 4; ++j) {
        int e = e0 + j * 256;
        s[j] = 0; w[j] = 0.f; drv[j] = make_int2(0, 0);
        if (e < E) {
            if (fl) s[j] = (int)__builtin_nontemporal_load(((const long long*)raw) + e);
            else    s[j] = __builtin_nontemporal_load(((const int*)raw) + e);
            w[j] = __builtin_nontemporal_load(ea + e);
            drv[j] = dr[e];
        }
    }
    int slot[4];
#pragma unroll
    for (int j = 0; j < 4; ++j) {
        int e = e0 + j * 256;
        if (e < E) slot[j] = base[drv[j].x] + drv[j].y;
    }
#pragma unroll
    for (int j = 0; j < 4; ++j) {
        int e = e0 + j * 256;
        if (e < E) {
            long long packed = (unsigned int)s[j] | ((long long)__float_as_int(w[j]) << 32);
            __builtin_nontemporal_store(packed, csr + slot[j]);
        }
    }
}

// ---------------- gather1: aggm[n] = (sum_e w*x[src])/max(deg,1) -------------
__global__ __launch_bounds__(256) void gather1(
    const float* __restrict__ x, const int2* __restrict__ csr,
    const int* __restrict__ base, const int* __restrict__ deg,
    float* __restrict__ aggm, int N)
{
    int lane = threadIdx.x & 63;
    int wid = blockIdx.x * 4 + (threadIdx.x >> 6);
    int stride = gridDim.x * 4;
    for (int n = wid; n < N; n += stride) {
        int b = __builtin_amdgcn_readfirstlane(base[n]);
        int dg = __builtin_amdgcn_readfirstlane(deg[n]);
        float acc0 = 0.f, acc1 = 0.f, acc2 = 0.f, acc3 = 0.f;
        int i = b, e = b + dg;
        for (; i + 8 <= e; i += 8) {
            int2 r0 = csr[i], r1 = csr[i + 1], r2 = csr[i + 2], r3 = csr[i + 3];
            int2 r4 = csr[i + 4], r5 = csr[i + 5], r6 = csr[i + 6], r7 = csr[i + 7];
            float v0 = x[(size_t)r0.x * 64 + lane];
            float v1 = x[(size_t)r1.x * 64 + lane];
            float v2 = x[(size_t)r2.x * 64 + lane];
            float v3 = x[(size_t)r3.x * 64 + lane];
            float v4 = x[(size_t)r4.x * 64 + lane];
            float v5 = x[(size_t)r5.x * 64 + lane];
            float v6 = x[(size_t)r6.x * 64 + lane];
            float v7 = x[(size_t)r7.x * 64 + lane];
            acc0 = fmaf(__int_as_float(r0.y), v0, acc0);
            acc1 = fmaf(__int_as_float(r1.y), v1, acc1);
            acc2 = fmaf(__int_as_float(r2.y), v2, acc2);
            acc3 = fmaf(__int_as_float(r3.y), v3, acc3);
            acc0 = fmaf(__int_as_float(r4.y), v4, acc0);
            acc1 = fmaf(__int_as_float(r5.y), v5, acc1);
            acc2 = fmaf(__int_as_float(r6.y), v6, acc2);
            acc3 = fmaf(__int_as_float(r7.y), v7, acc3);
        }
        for (; i + 4 <= e; i += 4) {
            int2 r0 = csr[i], r1 = csr[i + 1], r2 = csr[i + 2], r3 = csr[i + 3];
            acc0 = fmaf(__int_as_float(r0.y), x[(size_t)r0.x * 64 + lane], acc0);
            acc1 = fmaf(__int_as_float(r1.y), x[(size_t)r1.x * 64 + lane], acc1);
            acc2 = fmaf(__int_as_float(r2.y), x[(size_t)r2.x * 64 + lane], acc2);
            acc3 = fmaf(__int_as_float(r3.y), x[(size_t)r3.x * 64 + lane], acc3);
        }
        for (; i < e; ++i) {
            int2 r = csr[i];
            acc0 = fmaf(__int_as_float(r.y), x[(size_t)r.x * 64 + lane], acc0);
        }
        float inv = 1.0f / fmaxf((float)dg, 1.0f);
        aggm[(size_t)n * 64 + lane] = ((acc0 + acc1) + (acc2 + acc3)) * inv;
    }
}

// ---------------- node_fused v2: lane=node, scalar weights -------------------
__global__ __launch_bounds__(256) void node_fused(
    const float* __restrict__ x, const float* __restrict__ aggm,
    const float* __restrict__ W1relT, const float* __restrict__ brel1,
    const float* __restrict__ W1rootT, const float* __restrict__ W2T,
    const float* __restrict__ brel2,
    float* __restrict__ hr, float* __restrict__ hro, int N)
{
    __shared__ float A[64 * 65];
    int t = threadIdx.x;
    int lane = t & 63;
    int fbase = __builtin_amdgcn_readfirstlane((t >> 6) * 16);
    int n0 = blockIdx.x * 64;
    int rem = N - n0; if (rem > 64) rem = 64;

#define STAGE(SRC)                                                          \
    for (int idx = t; idx < 1024; idx += 256) {                             \
        int m = idx >> 4, c = idx & 15;                                     \
        int srcn = n0 + ((m < rem) ? m : 0);                                \
        float4 v = *(const float4*)((SRC) + (size_t)srcn * 64 + c * 4);     \
        float* dst = &A[m * 65 + c * 4];                                    \
        dst[0] = v.x; dst[1] = v.y; dst[2] = v.z; dst[3] = v.w;             \
    }

#define PHASE(WT_)                                                          \
    _Pragma("unroll 4")                                                     \
    for (int k = 0; k < 64; ++k) {                                          \
        float a = A[lane * 65 + k];                                         \
        const float* wk = (WT_) + k * 64 + fbase;                           \
        float4 w0 = *(const float4*)(wk);                                   \
        float4 w1 = *(const float4*)(wk + 4);                               \
        float4 w2 = *(const float4*)(wk + 8);                               \
        float4 w3 = *(const float4*)(wk + 12);                              \
        acc0.x = fmaf(a, w0.x, acc0.x); acc0.y = fmaf(a, w0.y, acc0.y);     \
        acc0.z = fmaf(a, w0.z, acc0.z); acc0.w = fmaf(a, w0.w, acc0.w);     \
        acc1.x = fmaf(a, w1.x, acc1.x); acc1.y = fmaf(a, w1.y, acc1.y);     \
        acc1.z = fmaf(a, w1.z, acc1.z); acc1.w = fmaf(a, w1.w, acc1.w);     \
        acc2.x = fmaf(a, w2.x, acc2.x); acc2.y = fmaf(a, w2.y, acc2.y);     \
        acc2.z = fmaf(a, w2.z, acc2.z); acc2.w = fmaf(a, w2.w, acc2.w);     \
        acc3.x = fmaf(a, w3.x, acc3.x); acc3.y = fmaf(a, w3.y, acc3.y);     \
        acc3.z = fmaf(a, w3.z, acc3.z); acc3.w = fmaf(a, w3.w, acc3.w);     \
    }

    // ---- phase 1: acc = b1 + aggm @ Wrel1^T (f-slice) ----
    STAGE(aggm)
    float4 acc0 = *(const float4*)(brel1 + fbase);
    float4 acc1 = *(const float4*)(brel1 + fbase + 4);
    float4 acc2 = *(const float4*)(brel1 + fbase + 8);
    float4 acc3 = *(const float4*)(brel1 + fbase + 12);
    __syncthreads();
    PHASE(W1relT)
    __syncthreads();

    // ---- phase 2: acc += x @ Wroot1^T ; h = sigmoid(acc) ----
    STAGE(x)
    __syncthreads();
    PHASE(W1rootT)
    acc0.x = 1.f / (1.f + __expf(-acc0.x)); acc0.y = 1.f / (1.f + __expf(-acc0.y));
    acc0.z = 1.f / (1.f + __expf(-acc0.z)); acc0.w = 1.f / (1.f + __expf(-acc0.w));
    acc1.x = 1.f / (1.f + __expf(-acc1.x)); acc1.y = 1.f / (1.f + __expf(-acc1.y));
    acc1.z = 1.f / (1.f + __expf(-acc1.z)); acc1.w = 1.f / (1.f + __expf(-acc1.w));
    acc2.x = 1.f / (1.f + __expf(-acc2.x)); acc2.y = 1.f / (1.f + __expf(-acc2.y));
    acc2.z = 1.f / (1.f + __expf(-acc2.z)); acc2.w = 1.f / (1.f + __expf(-acc2.w));
    acc3.x = 1.f / (1.f + __expf(-acc3.x)); acc3.y = 1.f / (1.f + __expf(-acc3.y));
    acc3.z = 1.f / (1.f + __expf(-acc3.z)); acc3.w = 1.f / (1.f + __expf(-acc3.w));
    __syncthreads();

    // ---- h -> LDS tile ----
    {
        float* hrow = &A[lane * 65 + fbase];
        hrow[0] = acc0.x; hrow[1] = acc0.y; hrow[2] = acc0.z; hrow[3] = acc0.w;
        hrow[4] = acc1.x; hrow[5] = acc1.y; hrow[6] = acc1.z; hrow[7] = acc1.w;
        hrow[8] = acc2.x; hrow[9] = acc2.y; hrow[10] = acc2.z; hrow[11] = acc2.w;
        hrow[12] = acc3.x; hrow[13] = acc3.y; hrow[14] = acc3.z; hrow[15] = acc3.w;
    }
    __syncthreads();

    // ---- phase 3: out2[j-slice] = h @ W2T (+b2 for j>=32) ----
    if (fbase < 32) {
        acc0 = make_float4(0.f, 0.f, 0.f, 0.f);
        acc1 = acc0; acc2 = acc0; acc3 = acc0;
    } else {
        acc0 = *(const float4*)(brel2 + fbase - 32);
        acc1 = *(const float4*)(brel2 + fbase - 28);
        acc2 = *(const float4*)(brel2 + fbase - 24);
        acc3 = *(const float4*)(brel2 + fbase - 20);
    }
    PHASE(W2T)
    __syncthreads();

    // ---- out2 -> LDS, then coalesced global write ----
    {
        float* orow = &A[lane * 65 + fbase];
        orow[0] = acc0.x; orow[1] = acc0.y; orow[2] = acc0.z; orow[3] = acc0.w;
        orow[4] = acc1.x; orow[5] = acc1.y; orow[6] = acc1.z; orow[7] = acc1.w;
        orow[8] = acc2.x; orow[9] = acc2.y; orow[10] = acc2.z; orow[11] = acc2.w;
        orow[12] = acc3.x; orow[13] = acc3.y; orow[14] = acc3.z; orow[15] = acc3.w;
    }
    __syncthreads();
    for (int idx = t; idx < 1024; idx += 256) {
        int m = idx >> 4, c = idx & 15;
        if (m < rem) {
            const float* src = &A[m * 65 + c * 4];
            float4 v = make_float4(src[0], src[1], src[2], src[3]);
            if (c < 8) *(float4*)(hr + (size_t)(n0 + m) * 32 + c * 4) = v;
            else       *(float4*)(hro + (size_t)(n0 + m) * 32 + (c - 8) * 4) = v;
        }
    }
#undef STAGE
#undef PHASE
}

// ---------------- gather2 + epilogue: out = agg2/deg + hro -------------------
__global__ __launch_bounds__(256) void gather2(
    const float* __restrict__ hr, const float* __restrict__ hro,
    const int2* __restrict__ csr, const int* __restrict__ base,
    const int* __restrict__ deg, float* __restrict__ out, int N)
{
    int lane = threadIdx.x & 63;
    int j = lane & 31, half = lane >> 5;
    int wid = blockIdx.x * 4 + (threadIdx.x >> 6);
    int stride = gridDim.x * 4;
    for (int n = wid; n < N; n += stride) {
        int b = __builtin_amdgcn_readfirstlane(base[n]);
        int dg = __builtin_amdgcn_readfirstlane(deg[n]);
        float a0 = 0.f, a1 = 0.f, a2 = 0.f, a3 = 0.f;
        int i = b + half, e = b + dg;
        for (; i + 8 <= e + half; i += 8) {
            int2 r0 = csr[i], r1 = csr[i + 2], r2 = csr[i + 4], r3 = csr[i + 6];
            a0 = fmaf(__int_as_float(r0.y), hr[(size_t)r0.x * 32 + j], a0);
            a1 = fmaf(__int_as_float(r1.y), hr[(size_t)r1.x * 32 + j], a1);
            a2 = fmaf(__int_as_float(r2.y), hr[(size_t)r2.x * 32 + j], a2);
            a3 = fmaf(__int_as_float(r3.y), hr[(size_t)r3.x * 32 + j], a3);
        }
        for (; i < e; i += 2) {
            int2 r = csr[i];
            a0 = fmaf(__int_as_float(r.y), hr[(size_t)r.x * 32 + j], a0);
        }
        float acc = (a0 + a1) + (a2 + a3);
        acc += __shfl_xor(acc, 32);
        if (half == 0) {
            float inv = 1.0f / fmaxf((float)dg, 1.0f);
            out[(size_t)n * 32 + j] = acc * inv + hro[(size_t)n * 32 + j];
        }
    }
}

extern "C" void kernel_launch(void* const* d_in, const int* in_sizes, int n_in,
                              void* d_out, int out_size, void* d_ws, size_t ws_size,
                              hipStream_t stream) {
    const float* x      = (const float*)d_in[0];
    const void*  ei_raw = d_in[1];
    const float* ea     = (const float*)d_in[2];
    const float* Wrel1  = (const float*)d_in[3];
    const float* brel1  = (const float*)d_in[4];
    const float* Wroot1 = (const float*)d_in[5];
    const float* Wrel2  = (const float*)d_in[6];
    const float* brel2  = (const float*)d_in[7];
    const float* Wroot2 = (const float*)d_in[8];
    float* out = (float*)d_out;

    const int N = in_sizes[0] / NF;     // 100000
    const int E = in_sizes[2];          // 1000000

    // workspace layout
    long long* csr = (long long*)d_ws;              // E (8 MB)
    int*   deg     = (int*)(csr + E);               // N
    int*   base    = deg + N;                       // N
    int*   bsums   = base + N;                      // 256
    int*   flag    = bsums + 256;                   // 1 (+3 pad)
    int2*  dr      = (int2*)(flag + 4);             // E (8 MB) packed (dst,rank)
    float* aggm    = (float*)(dr + E);              // N*64
    float* hr      = aggm + (size_t)N * 64;         // N*32
    float* hro     = hr + (size_t)N * 32;           // N*32
    float* W1relT  = hro + (size_t)N * 32;          // 4096
    float* W1rootT = W1relT + 4096;                 // 4096
    float* W2T     = W1rootT + 4096;                // 4096

    const int nb1 = (N + 1023) / 1024;
    const int ebq = (E + 1023) / 1024;              // blocks for 4-edge/thread

    hipMemsetAsync(deg, 0, (size_t)N * sizeof(int), stream);
    detect_i64<<<1, 256, 0, stream>>>((const unsigned*)ei_raw, flag, E);
    wprep<<<1, 256, 0, stream>>>(Wrel1, Wroot1, Wrel2, Wroot2, W1relT, W1rootT, W2T);
    hist<<<ebq, 256, 0, stream>>>(ei_raw, flag, deg, dr, E);
    scan_k1<<<nb1, 1024, 0, stream>>>(deg, base, bsums, N);
    scan_k2<<<1, 256, 0, stream>>>(bsums, nb1);
    scan_k3<<<nb1, 1024, 0, stream>>>(base, bsums, N);
    fill_csr<<<ebq, 256, 0, stream>>>(ei_raw, flag, ea, dr, base, csr, E);

    gather1<<<2048, 256, 0, stream>>>(x, (const int2*)csr, base, deg, aggm, N);
    node_fused<<<(N + 63) / 64, 256, 0, stream>>>(x, aggm, W1relT, brel1, W1rootT,
                                                  W2T, brel2, hr, hro, N);
    gather2<<<2048, 256, 0, stream>>>(hr, hro, (const int2*)csr, base, deg, out, N);
}